// Round 1
// baseline (355.215 us; speedup 1.0000x reference)
//
#include <hip/hip_runtime.h>
#include <hip/hip_bf16.h>

typedef __attribute__((ext_vector_type(8))) short s8v;   // 8 x bf16 raw (4 VGPRs)
typedef __attribute__((ext_vector_type(4))) float f4v;   // MFMA accumulator

__device__ __forceinline__ ushort f2bf(float f) {
    union { float f; unsigned u; } cv; cv.f = f;
    unsigned u = cv.u;
    unsigned lsb = (u >> 16) & 1u;
    u += 0x7fffu + lsb;          // RNE round to bf16
    return (ushort)(u >> 16);
}

// ---------------- cast fp32 -> bf16 (vectorized) ----------------
__global__ void cast_bf16_kernel(const float* __restrict__ in, ushort* __restrict__ out, int n4) {
    int i = blockIdx.x * blockDim.x + threadIdx.x;
    if (i >= n4) return;
    float4 v = reinterpret_cast<const float4*>(in)[i];
    ushort4 o;
    o.x = f2bf(v.x); o.y = f2bf(v.y); o.z = f2bf(v.z); o.w = f2bf(v.w);
    reinterpret_cast<ushort4*>(out)[i] = o;
}

// ---------------- transpose + cast: in[R][C] fp32 -> out[C][R] bf16 ----------------
__global__ void transpose_cast_kernel(const float* __restrict__ in, ushort* __restrict__ out,
                                      int R, int C) {
    __shared__ float tile[32][33];
    int c0 = blockIdx.x * 32, r0 = blockIdx.y * 32;
    int tx = threadIdx.x & 31, ty = threadIdx.x >> 5;  // ty in 0..7
    #pragma unroll
    for (int i = 0; i < 32; i += 8)
        tile[ty + i][tx] = in[(size_t)(r0 + ty + i) * C + c0 + tx];
    __syncthreads();
    #pragma unroll
    for (int i = 0; i < 32; i += 8)
        out[(size_t)(c0 + ty + i) * R + r0 + tx] = f2bf(tile[tx][ty + i]);
}

// ---------------- bf16 MFMA GEMM: C[M][N] = A[M][K] * Bt[N][K]^T + bias ----------------
// 128x128 tile, BK=64, 4 waves (2x2), each wave 64x64 via 4x4 blocks of 16x16x32 MFMA.
template <bool OUT_BF16>
__global__ __launch_bounds__(256) void gemm_bt_kernel(
    const ushort* __restrict__ A, const ushort* __restrict__ Bt,
    const float* __restrict__ bias, void* __restrict__ Cout,
    int M, int N, int K)
{
    __shared__ ushort As[128][72];   // +8 pad: row stride 144B -> 2-way max on b128 reads
    __shared__ ushort Bs[128][72];
    const int t = threadIdx.x;
    const int m0 = blockIdx.y * 128, n0 = blockIdx.x * 128;
    const int wave = t >> 6, lane = t & 63;
    const int lr = lane & 15, lg = lane >> 4;
    const int wm = (wave >> 1) * 64, wn = (wave & 1) * 64;

    f4v acc[4][4];
    #pragma unroll
    for (int i = 0; i < 4; i++)
        #pragma unroll
        for (int j = 0; j < 4; j++)
            acc[i][j] = (f4v){0.f, 0.f, 0.f, 0.f};

    for (int k0 = 0; k0 < K; k0 += 64) {
        __syncthreads();
        #pragma unroll
        for (int i = 0; i < 4; i++) {
            int c = t + i * 256;            // 0..1023
            int row = c >> 3, kc = (c & 7) << 3;
            s8v av = *reinterpret_cast<const s8v*>(A + (size_t)(m0 + row) * K + k0 + kc);
            *reinterpret_cast<s8v*>(&As[row][kc]) = av;
            s8v bv = *reinterpret_cast<const s8v*>(Bt + (size_t)(n0 + row) * K + k0 + kc);
            *reinterpret_cast<s8v*>(&Bs[row][kc]) = bv;
        }
        __syncthreads();
        #pragma unroll
        for (int ks = 0; ks < 64; ks += 32) {
            s8v af[4], bfr[4];
            #pragma unroll
            for (int mb = 0; mb < 4; mb++)
                af[mb] = *reinterpret_cast<const s8v*>(&As[wm + mb * 16 + lr][ks + lg * 8]);
            #pragma unroll
            for (int nb = 0; nb < 4; nb++)
                bfr[nb] = *reinterpret_cast<const s8v*>(&Bs[wn + nb * 16 + lr][ks + lg * 8]);
            #pragma unroll
            for (int mb = 0; mb < 4; mb++)
                #pragma unroll
                for (int nb = 0; nb < 4; nb++)
                    acc[mb][nb] = __builtin_amdgcn_mfma_f32_16x16x32_bf16(af[mb], bfr[nb], acc[mb][nb], 0, 0, 0);
        }
    }

    #pragma unroll
    for (int mb = 0; mb < 4; mb++) {
        #pragma unroll
        for (int nb = 0; nb < 4; nb++) {
            int col = n0 + wn + nb * 16 + lr;
            float bv = bias[col];
            #pragma unroll
            for (int r = 0; r < 4; r++) {
                int row = m0 + wm + mb * 16 + lg * 4 + r;
                float val = acc[mb][nb][r] + bv;
                if (OUT_BF16)
                    reinterpret_cast<ushort*>(Cout)[(size_t)row * N + col] = f2bf(val);
                else
                    reinterpret_cast<float*>(Cout)[(size_t)row * N + col] = val;
            }
        }
    }
}

// ---------------- flash attention with clipped rel-pos bias + causal mask ----------------
// Grid: (T/64, B*16). Block = 256 (4 waves). Wave w owns q rows [qb+16w, qb+16w+16).
// qkv layout: [B*T][3072], q at h*64, k at 1024+h*64, v at 2048+h*64.
__global__ __launch_bounds__(256) void attn_kernel(
    const ushort* __restrict__ qkv, const float* __restrict__ rel_emb,
    ushort* __restrict__ attn_out, int T)
{
    __shared__ float rel_lds[257];
    __shared__ ushort vt[64][72];        // V^T tile: vt[d][s]
    __shared__ ushort p_lds[4][16][72];  // per-wave P[q][s] for A-fragment transpose

    const int t = threadIdx.x;
    const int qb = blockIdx.x * 64;
    const int bh = blockIdx.y;
    const int b = bh >> 4, h = bh & 15;
    const size_t rowb = (size_t)b * T;

    for (int i = t; i < 257; i += 256) rel_lds[i] = rel_emb[i * 16 + h];

    const int wave = t >> 6, lane = t & 63;
    const int lr = lane & 15, lg = lane >> 4;
    const int qrow = qb + wave * 16 + lr;

    // hoisted Q fragments (A-operand: row=lane&15, k=(lane>>4)*8+i, chunks k0/k32)
    const ushort* qptr = qkv + (rowb + qrow) * 3072 + h * 64;
    s8v qf0 = *reinterpret_cast<const s8v*>(qptr + lg * 8);
    s8v qf1 = *reinterpret_cast<const s8v*>(qptr + 32 + lg * 8);

    float m_r[4], l_r[4];
    f4v o_acc[4];
    #pragma unroll
    for (int r = 0; r < 4; r++) { m_r[r] = -3.0e38f; l_r[r] = 0.f; }
    #pragma unroll
    for (int d = 0; d < 4; d++) o_acc[d] = (f4v){0.f, 0.f, 0.f, 0.f};

    for (int sb = 0; sb < qb + 64; sb += 64) {
        __syncthreads();   // previous PV done before vt overwrite
        // stage V^T (transposed) into LDS
        #pragma unroll
        for (int i = 0; i < 2; i++) {
            int c = t + i * 256;                 // 0..511
            int s = c >> 3, dc = (c & 7) << 3;
            s8v vv = *reinterpret_cast<const s8v*>(qkv + (rowb + sb + s) * 3072 + 2048 + h * 64 + dc);
            #pragma unroll
            for (int j = 0; j < 8; j++) vt[dc + j][s] = (ushort)vv[j];
        }
        __syncthreads();

        // S = Q K^T (B-operand from global: col=s=lane&15, k=d contiguous)
        f4v sacc[4];
        #pragma unroll
        for (int cb = 0; cb < 4; cb++) sacc[cb] = (f4v){0.f, 0.f, 0.f, 0.f};
        #pragma unroll
        for (int cb = 0; cb < 4; cb++) {
            const ushort* kptr = qkv + (rowb + sb + cb * 16 + lr) * 3072 + 1024 + h * 64;
            s8v kf0 = *reinterpret_cast<const s8v*>(kptr + lg * 8);
            s8v kf1 = *reinterpret_cast<const s8v*>(kptr + 32 + lg * 8);
            sacc[cb] = __builtin_amdgcn_mfma_f32_16x16x32_bf16(qf0, kf0, sacc[cb], 0, 0, 0);
            sacc[cb] = __builtin_amdgcn_mfma_f32_16x16x32_bf16(qf1, kf1, sacc[cb], 0, 0, 0);
        }

        // scale + rel bias + causal mask (S layout: col s = lane&15, row q = lg*4+r)
        #pragma unroll
        for (int cb = 0; cb < 4; cb++) {
            int s = sb + cb * 16 + lr;
            #pragma unroll
            for (int r = 0; r < 4; r++) {
                int q = qb + wave * 16 + lg * 4 + r;
                int rel = s - q;
                rel = (rel < -128 ? -128 : (rel > 128 ? 128 : rel)) + 128;
                float val = sacc[cb][r] * 0.125f + rel_lds[rel];
                if (s > q) val = -3.0e38f;
                sacc[cb][r] = val;
            }
        }

        // online softmax: per q-row reduce over s (4 blocks in-lane + 16-lane shfl tree)
        #pragma unroll
        for (int r = 0; r < 4; r++) {
            float mx = fmaxf(fmaxf(sacc[0][r], sacc[1][r]), fmaxf(sacc[2][r], sacc[3][r]));
            #pragma unroll
            for (int off = 1; off < 16; off <<= 1)
                mx = fmaxf(mx, __shfl_xor(mx, off, 64));
            float mnew = fmaxf(m_r[r], mx);
            float alpha = exp2f((m_r[r] - mnew) * 1.44269504f);
            m_r[r] = mnew;
            l_r[r] *= alpha;
            #pragma unroll
            for (int d = 0; d < 4; d++) o_acc[d][r] *= alpha;
            float sum = 0.f;
            #pragma unroll
            for (int cb = 0; cb < 4; cb++) {
                float p = exp2f((sacc[cb][r] - mnew) * 1.44269504f);
                sacc[cb][r] = p;
                sum += p;
            }
            #pragma unroll
            for (int off = 1; off < 16; off <<= 1)
                sum += __shfl_xor(sum, off, 64);
            l_r[r] += sum;
        }

        // transpose P through LDS (acc layout -> A-fragment layout)
        #pragma unroll
        for (int cb = 0; cb < 4; cb++)
            #pragma unroll
            for (int r = 0; r < 4; r++)
                p_lds[wave][lg * 4 + r][cb * 16 + lr] = f2bf(sacc[cb][r]);
        __syncthreads();

        // O += P V
        #pragma unroll
        for (int ch = 0; ch < 2; ch++) {
            s8v pf = *reinterpret_cast<const s8v*>(&p_lds[wave][lr][ch * 32 + lg * 8]);
            #pragma unroll
            for (int d = 0; d < 4; d++) {
                s8v vf = *reinterpret_cast<const s8v*>(&vt[d * 16 + lr][ch * 32 + lg * 8]);
                o_acc[d] = __builtin_amdgcn_mfma_f32_16x16x32_bf16(pf, vf, o_acc[d], 0, 0, 0);
            }
        }
    }

    // epilogue: O /= l, store bf16 [B*T][1024]
    #pragma unroll
    for (int r = 0; r < 4; r++) {
        float inv = 1.0f / l_r[r];
        int row = qb + wave * 16 + lg * 4 + r;
        #pragma unroll
        for (int d = 0; d < 4; d++) {
            float val = o_acc[d][r] * inv;
            attn_out[(rowb + row) * 1024 + h * 64 + d * 16 + lr] = f2bf(val);
        }
    }
}

extern "C" void kernel_launch(void* const* d_in, const int* in_sizes, int n_in,
                              void* d_out, int out_size, void* d_ws, size_t ws_size,
                              hipStream_t stream) {
    const float* x       = (const float*)d_in[0];   // [B,T,1024]
    const float* Wqkv    = (const float*)d_in[1];   // [1024,3072]
    const float* bqkv    = (const float*)d_in[2];   // [3072]
    const float* Wout    = (const float*)d_in[3];   // [1024,1024]
    const float* bout    = (const float*)d_in[4];   // [1024]
    const float* rel_emb = (const float*)d_in[5];   // [257,16]
    float* out = (float*)d_out;

    const int M = in_sizes[0] / 1024;   // B*T = 4096
    const int T = 2048;
    const int B = M / T;

    // workspace layout (all 16B-aligned): ~48 MiB total
    ushort* x_bf = (ushort*)d_ws;                        // M*1024 bf16
    ushort* Wq_t = x_bf + (size_t)M * 1024;              // 3072*1024
    ushort* Wo_t = Wq_t + (size_t)3072 * 1024;           // 1024*1024
    ushort* qkv  = Wo_t + (size_t)1024 * 1024;           // M*3072
    ushort* attn = qkv + (size_t)M * 3072;               // M*1024

    hipLaunchKernelGGL(cast_bf16_kernel, dim3((M * 1024 / 4 + 255) / 256), dim3(256), 0, stream,
                       x, x_bf, M * 1024 / 4);
    hipLaunchKernelGGL(transpose_cast_kernel, dim3(3072 / 32, 1024 / 32), dim3(256), 0, stream,
                       Wqkv, Wq_t, 1024, 3072);
    hipLaunchKernelGGL(transpose_cast_kernel, dim3(1024 / 32, 1024 / 32), dim3(256), 0, stream,
                       Wout, Wo_t, 1024, 1024);
    hipLaunchKernelGGL((gemm_bt_kernel<true>), dim3(3072 / 128, M / 128), dim3(256), 0, stream,
                       x_bf, Wq_t, bqkv, (void*)qkv, M, 3072, 1024);
    hipLaunchKernelGGL(attn_kernel, dim3(T / 64, B * 16), dim3(256), 0, stream,
                       qkv, rel_emb, attn, T);
    hipLaunchKernelGGL((gemm_bt_kernel<false>), dim3(1024 / 128, M / 128), dim3(256), 0, stream,
                       attn, Wo_t, bout, (void*)out, M, 1024, 1024);
}

// Round 2
// 306.119 us; speedup vs baseline: 1.1604x; 1.1604x over previous
//
#include <hip/hip_runtime.h>
#include <hip/hip_bf16.h>

typedef __attribute__((ext_vector_type(8))) short s8v;   // 8 x bf16 raw (4 VGPRs)
typedef __attribute__((ext_vector_type(4))) float f4v;   // MFMA accumulator

__device__ __forceinline__ ushort f2bf(float f) {
    union { float f; unsigned u; } cv; cv.f = f;
    unsigned u = cv.u;
    unsigned lsb = (u >> 16) & 1u;
    u += 0x7fffu + lsb;          // RNE round to bf16
    return (ushort)(u >> 16);
}

// ---------------- cast fp32 -> bf16 (vectorized) ----------------
__global__ void cast_bf16_kernel(const float* __restrict__ in, ushort* __restrict__ out, int n4) {
    int i = blockIdx.x * blockDim.x + threadIdx.x;
    if (i >= n4) return;
    float4 v = reinterpret_cast<const float4*>(in)[i];
    ushort4 o;
    o.x = f2bf(v.x); o.y = f2bf(v.y); o.z = f2bf(v.z); o.w = f2bf(v.w);
    reinterpret_cast<ushort4*>(out)[i] = o;
}

// ---------------- transpose + cast: in[R][C] fp32 -> out[C][R] bf16 ----------------
__global__ void transpose_cast_kernel(const float* __restrict__ in, ushort* __restrict__ out,
                                      int R, int C) {
    __shared__ float tile[32][33];
    int c0 = blockIdx.x * 32, r0 = blockIdx.y * 32;
    int tx = threadIdx.x & 31, ty = threadIdx.x >> 5;  // ty in 0..7
    #pragma unroll
    for (int i = 0; i < 32; i += 8)
        tile[ty + i][tx] = in[(size_t)(r0 + ty + i) * C + c0 + tx];
    __syncthreads();
    #pragma unroll
    for (int i = 0; i < 32; i += 8)
        out[(size_t)(c0 + ty + i) * R + r0 + tx] = f2bf(tile[tx][ty + i]);
}

// ---------------- V transpose: qkv V part -> Vt[b*16+h][64 d][T s] bf16 ----------------
__global__ __launch_bounds__(256) void vtrans_kernel(
    const ushort* __restrict__ qkv, ushort* __restrict__ vt_g, int T)
{
    __shared__ ushort tile[64][72];
    const int sb = blockIdx.x * 64, bh = blockIdx.y;
    const int b = bh >> 4, h = bh & 15;
    const int t = threadIdx.x;
    const int r0 = t >> 3, c0 = (t & 7) * 8;
    const ushort* vsrc = qkv + (size_t)b * T * 3072 + 2048 + h * 64;
    *(s8v*)&tile[r0][c0]      = *(const s8v*)(vsrc + (size_t)(sb + r0) * 3072 + c0);
    *(s8v*)&tile[32 + r0][c0] = *(const s8v*)(vsrc + (size_t)(sb + 32 + r0) * 3072 + c0);
    __syncthreads();
    ushort* vdst = vt_g + (size_t)bh * 64 * T;
    s8v o0, o1;
    #pragma unroll
    for (int j = 0; j < 8; j++) {
        o0[j] = (short)tile[c0 + j][r0];
        o1[j] = (short)tile[c0 + j][32 + r0];
    }
    *(s8v*)(vdst + (size_t)r0 * T + sb + c0)        = o0;
    *(s8v*)(vdst + (size_t)(32 + r0) * T + sb + c0) = o1;
}

// ---------------- bf16 MFMA GEMM: C[M][N] = A[M][K] * Bt[N][K]^T + bias ----------------
template <bool OUT_BF16>
__global__ __launch_bounds__(256) void gemm_bt_kernel(
    const ushort* __restrict__ A, const ushort* __restrict__ Bt,
    const float* __restrict__ bias, void* __restrict__ Cout,
    int M, int N, int K)
{
    __shared__ ushort As[128][72];
    __shared__ ushort Bs[128][72];
    const int t = threadIdx.x;
    const int m0 = blockIdx.y * 128, n0 = blockIdx.x * 128;
    const int wave = t >> 6, lane = t & 63;
    const int lr = lane & 15, lg = lane >> 4;
    const int wm = (wave >> 1) * 64, wn = (wave & 1) * 64;

    f4v acc[4][4];
    #pragma unroll
    for (int i = 0; i < 4; i++)
        #pragma unroll
        for (int j = 0; j < 4; j++)
            acc[i][j] = (f4v){0.f, 0.f, 0.f, 0.f};

    for (int k0 = 0; k0 < K; k0 += 64) {
        __syncthreads();
        #pragma unroll
        for (int i = 0; i < 4; i++) {
            int c = t + i * 256;
            int row = c >> 3, kc = (c & 7) << 3;
            s8v av = *reinterpret_cast<const s8v*>(A + (size_t)(m0 + row) * K + k0 + kc);
            *reinterpret_cast<s8v*>(&As[row][kc]) = av;
            s8v bv = *reinterpret_cast<const s8v*>(Bt + (size_t)(n0 + row) * K + k0 + kc);
            *reinterpret_cast<s8v*>(&Bs[row][kc]) = bv;
        }
        __syncthreads();
        #pragma unroll
        for (int ks = 0; ks < 64; ks += 32) {
            s8v af[4], bfr[4];
            #pragma unroll
            for (int mb = 0; mb < 4; mb++)
                af[mb] = *reinterpret_cast<const s8v*>(&As[wm + mb * 16 + lr][ks + lg * 8]);
            #pragma unroll
            for (int nb = 0; nb < 4; nb++)
                bfr[nb] = *reinterpret_cast<const s8v*>(&Bs[wn + nb * 16 + lr][ks + lg * 8]);
            #pragma unroll
            for (int mb = 0; mb < 4; mb++)
                #pragma unroll
                for (int nb = 0; nb < 4; nb++)
                    acc[mb][nb] = __builtin_amdgcn_mfma_f32_16x16x32_bf16(af[mb], bfr[nb], acc[mb][nb], 0, 0, 0);
        }
    }

    #pragma unroll
    for (int mb = 0; mb < 4; mb++) {
        #pragma unroll
        for (int nb = 0; nb < 4; nb++) {
            int col = n0 + wn + nb * 16 + lr;
            float bv = bias[col];
            #pragma unroll
            for (int r = 0; r < 4; r++) {
                int row = m0 + wm + mb * 16 + lg * 4 + r;
                float val = acc[mb][nb][r] + bv;
                if (OUT_BF16)
                    reinterpret_cast<ushort*>(Cout)[(size_t)row * N + col] = f2bf(val);
                else
                    reinterpret_cast<float*>(Cout)[(size_t)row * N + col] = val;
            }
        }
    }
}

// ---------------- flash attention with clipped rel-pos bias + causal mask ----------------
// Grid: (T/64 reversed, B*16). Block = 256 (4 waves). Wave w owns q rows [qb+16w, qb+16w+16).
// K staged cooperatively in LDS; V^T staged from pre-transposed vt_g; reg double-buffer (T14).
__global__ __launch_bounds__(256) void attn_kernel(
    const ushort* __restrict__ qkv, const ushort* __restrict__ vt_g,
    const float* __restrict__ rel_emb, ushort* __restrict__ attn_out, int T)
{
    __shared__ ushort Ks[64][72];        // K[s][kc], pad 72 -> 2-way-free b128 reads
    __shared__ ushort Vs[64][72];        // V^T tile: Vs[d][s]
    __shared__ ushort p_lds[4][16][72];  // per-wave P[q][s] (wave-private, no barrier)
    __shared__ float rel_lds[257];

    const int t = threadIdx.x;
    const int qb = (gridDim.x - 1 - blockIdx.x) * 64;   // heavy blocks dispatch first
    const int bh = blockIdx.y;
    const int b = bh >> 4, h = bh & 15;
    const size_t rowb = (size_t)b * T;

    for (int i = t; i < 257; i += 256) rel_lds[i] = rel_emb[i * 16 + h];

    const int wave = t >> 6, lane = t & 63;
    const int lr = lane & 15, lg = lane >> 4;

    // staging coords: chunk c in 0..511, row=c>>3, col=(c&7)*8 (b128 per lane)
    const int sr = t >> 3, sc = (t & 7) * 8;
    const ushort* kbase = qkv + rowb * 3072 + 1024 + h * 64;   // + s*3072 + kc
    const ushort* vbase = vt_g + (size_t)bh * 64 * T;          // + d*T + s

    const int qrow = qb + wave * 16 + lr;
    const ushort* qptr = qkv + (rowb + qrow) * 3072 + h * 64;
    s8v qf0 = *(const s8v*)(qptr + lg * 8);
    s8v qf1 = *(const s8v*)(qptr + 32 + lg * 8);

    float m_r[4], l_r[4];
    f4v o_acc[4];
    #pragma unroll
    for (int r = 0; r < 4; r++) { m_r[r] = -3.0e38f; l_r[r] = 0.f; }
    #pragma unroll
    for (int d = 0; d < 4; d++) o_acc[d] = (f4v){0.f, 0.f, 0.f, 0.f};

    const int nt = qb / 64 + 1;

    // prologue: tile 0 -> regs
    s8v ka0 = *(const s8v*)(kbase + (size_t)sr * 3072 + sc);
    s8v ka1 = *(const s8v*)(kbase + (size_t)(32 + sr) * 3072 + sc);
    s8v va0 = *(const s8v*)(vbase + (size_t)sr * T + sc);
    s8v va1 = *(const s8v*)(vbase + (size_t)(32 + sr) * T + sc);

    for (int tt = 0; tt < nt; ++tt) {
        const int sb = tt * 64;
        __syncthreads();                 // previous tile's compute done
        *(s8v*)&Ks[sr][sc]      = ka0;
        *(s8v*)&Ks[32 + sr][sc] = ka1;
        *(s8v*)&Vs[sr][sc]      = va0;
        *(s8v*)&Vs[32 + sr][sc] = va1;
        __syncthreads();

        // prefetch next tile (flies during compute below)
        if (tt + 1 < nt) {
            const int sn = sb + 64;
            ka0 = *(const s8v*)(kbase + (size_t)(sn + sr) * 3072 + sc);
            ka1 = *(const s8v*)(kbase + (size_t)(sn + 32 + sr) * 3072 + sc);
            va0 = *(const s8v*)(vbase + (size_t)sr * T + sn + sc);
            va1 = *(const s8v*)(vbase + (size_t)(32 + sr) * T + sn + sc);
        }

        // S = Q K^T from LDS (B-operand: col=s=lane&15, k contiguous)
        f4v sacc[4];
        #pragma unroll
        for (int cb = 0; cb < 4; cb++) {
            sacc[cb] = (f4v){0.f, 0.f, 0.f, 0.f};
            s8v kf0 = *(const s8v*)&Ks[cb * 16 + lr][lg * 8];
            s8v kf1 = *(const s8v*)&Ks[cb * 16 + lr][32 + lg * 8];
            sacc[cb] = __builtin_amdgcn_mfma_f32_16x16x32_bf16(qf0, kf0, sacc[cb], 0, 0, 0);
            sacc[cb] = __builtin_amdgcn_mfma_f32_16x16x32_bf16(qf1, kf1, sacc[cb], 0, 0, 0);
        }

        // scale + rel bias + causal mask (S layout: col s = lr, row q = lg*4+r)
        #pragma unroll
        for (int cb = 0; cb < 4; cb++) {
            int s = sb + cb * 16 + lr;
            #pragma unroll
            for (int r = 0; r < 4; r++) {
                int q = qb + wave * 16 + lg * 4 + r;
                int rel = s - q;
                rel = (rel < -128 ? -128 : (rel > 128 ? 128 : rel)) + 128;
                float val = sacc[cb][r] * 0.125f + rel_lds[rel];
                if (s > q) val = -3.0e38f;
                sacc[cb][r] = val;
            }
        }

        // online softmax per q-row (4 in-lane blocks + 16-lane shfl trees)
        #pragma unroll
        for (int r = 0; r < 4; r++) {
            float mx = fmaxf(fmaxf(sacc[0][r], sacc[1][r]), fmaxf(sacc[2][r], sacc[3][r]));
            #pragma unroll
            for (int off = 1; off < 16; off <<= 1)
                mx = fmaxf(mx, __shfl_xor(mx, off, 64));
            float mnew = fmaxf(m_r[r], mx);
            float alpha = exp2f((m_r[r] - mnew) * 1.44269504f);
            m_r[r] = mnew;
            l_r[r] *= alpha;
            #pragma unroll
            for (int d = 0; d < 4; d++) o_acc[d][r] *= alpha;
            float sum = 0.f;
            #pragma unroll
            for (int cb = 0; cb < 4; cb++) {
                float p = exp2f((sacc[cb][r] - mnew) * 1.44269504f);
                sacc[cb][r] = p;
                sum += p;
            }
            #pragma unroll
            for (int off = 1; off < 16; off <<= 1)
                sum += __shfl_xor(sum, off, 64);
            l_r[r] += sum;
        }

        // transpose P through wave-private LDS (acc layout -> A-fragment layout)
        #pragma unroll
        for (int cb = 0; cb < 4; cb++)
            #pragma unroll
            for (int r = 0; r < 4; r++)
                p_lds[wave][lg * 4 + r][cb * 16 + lr] = f2bf(sacc[cb][r]);

        // O += P V  (V^T fragments from Vs: row=d, k=s contiguous)
        #pragma unroll
        for (int ch = 0; ch < 2; ch++) {
            s8v pf = *(const s8v*)&p_lds[wave][lr][ch * 32 + lg * 8];
            #pragma unroll
            for (int d = 0; d < 4; d++) {
                s8v vf = *(const s8v*)&Vs[d * 16 + lr][ch * 32 + lg * 8];
                o_acc[d] = __builtin_amdgcn_mfma_f32_16x16x32_bf16(pf, vf, o_acc[d], 0, 0, 0);
            }
        }
    }

    // epilogue: O /= l, store bf16 [B*T][1024]
    #pragma unroll
    for (int r = 0; r < 4; r++) {
        float inv = 1.0f / l_r[r];
        int row = qb + wave * 16 + lg * 4 + r;
        #pragma unroll
        for (int d = 0; d < 4; d++) {
            float val = o_acc[d][r] * inv;
            attn_out[(rowb + row) * 1024 + h * 64 + d * 16 + lr] = f2bf(val);
        }
    }
}

extern "C" void kernel_launch(void* const* d_in, const int* in_sizes, int n_in,
                              void* d_out, int out_size, void* d_ws, size_t ws_size,
                              hipStream_t stream) {
    const float* x       = (const float*)d_in[0];   // [B,T,1024]
    const float* Wqkv    = (const float*)d_in[1];   // [1024,3072]
    const float* bqkv    = (const float*)d_in[2];   // [3072]
    const float* Wout    = (const float*)d_in[3];   // [1024,1024]
    const float* bout    = (const float*)d_in[4];   // [1024]
    const float* rel_emb = (const float*)d_in[5];   // [257,16]
    float* out = (float*)d_out;

    const int M = in_sizes[0] / 1024;   // B*T = 4096
    const int T = 2048;
    const int B = M / T;

    // workspace layout (all 16B-aligned): ~56 MiB total
    ushort* x_bf = (ushort*)d_ws;                        // M*1024 bf16
    ushort* Wq_t = x_bf + (size_t)M * 1024;              // 3072*1024
    ushort* Wo_t = Wq_t + (size_t)3072 * 1024;           // 1024*1024
    ushort* qkv  = Wo_t + (size_t)1024 * 1024;           // M*3072
    ushort* attn = qkv + (size_t)M * 3072;               // M*1024
    ushort* vt_g = attn + (size_t)M * 1024;              // B*16*64*T = M*1024

    hipLaunchKernelGGL(cast_bf16_kernel, dim3((M * 1024 / 4 + 255) / 256), dim3(256), 0, stream,
                       x, x_bf, M * 1024 / 4);
    hipLaunchKernelGGL(transpose_cast_kernel, dim3(3072 / 32, 1024 / 32), dim3(256), 0, stream,
                       Wqkv, Wq_t, 1024, 3072);
    hipLaunchKernelGGL(transpose_cast_kernel, dim3(1024 / 32, 1024 / 32), dim3(256), 0, stream,
                       Wout, Wo_t, 1024, 1024);
    hipLaunchKernelGGL((gemm_bt_kernel<true>), dim3(3072 / 128, M / 128), dim3(256), 0, stream,
                       x_bf, Wq_t, bqkv, (void*)qkv, M, 3072, 1024);
    hipLaunchKernelGGL(vtrans_kernel, dim3(T / 64, B * 16), dim3(256), 0, stream,
                       qkv, vt_g, T);
    hipLaunchKernelGGL(attn_kernel, dim3(T / 64, B * 16), dim3(256), 0, stream,
                       qkv, vt_g, rel_emb, attn, T);
    hipLaunchKernelGGL((gemm_bt_kernel<false>), dim3(1024 / 128, M / 128), dim3(256), 0, stream,
                       attn, Wo_t, bout, (void*)out, M, 1024, 1024);
}

// Round 3
// 249.043 us; speedup vs baseline: 1.4263x; 1.2292x over previous
//
#include <hip/hip_runtime.h>
#include <hip/hip_bf16.h>

typedef __attribute__((ext_vector_type(8))) short s8v;   // 8 x bf16 raw (4 VGPRs)
typedef __attribute__((ext_vector_type(4))) float f4v;   // MFMA accumulator

__device__ __forceinline__ ushort f2bf(float f) {
    union { float f; unsigned u; } cv; cv.f = f;
    unsigned u = cv.u;
    unsigned lsb = (u >> 16) & 1u;
    u += 0x7fffu + lsb;          // RNE round to bf16
    return (ushort)(u >> 16);
}

// async global->LDS, 16B per lane; LDS dest is wave-uniform base + lane*16
typedef __attribute__((address_space(1))) void gvoid;
typedef __attribute__((address_space(3))) void lvoid;
__device__ __forceinline__ void gl_lds16(const ushort* g, ushort* l) {
    __builtin_amdgcn_global_load_lds((gvoid*)g, (lvoid*)l, 16, 0, 0);
}

// ---------------- cast fp32 -> bf16 (vectorized) ----------------
__global__ void cast_bf16_kernel(const float* __restrict__ in, ushort* __restrict__ out, int n4) {
    int i = blockIdx.x * blockDim.x + threadIdx.x;
    if (i >= n4) return;
    float4 v = reinterpret_cast<const float4*>(in)[i];
    ushort4 o;
    o.x = f2bf(v.x); o.y = f2bf(v.y); o.z = f2bf(v.z); o.w = f2bf(v.w);
    reinterpret_cast<ushort4*>(out)[i] = o;
}

// ---------------- transpose + cast: in[R][C] fp32 -> out[C][R] bf16 ----------------
__global__ void transpose_cast_kernel(const float* __restrict__ in, ushort* __restrict__ out,
                                      int R, int C) {
    __shared__ float tile[32][33];
    int c0 = blockIdx.x * 32, r0 = blockIdx.y * 32;
    int tx = threadIdx.x & 31, ty = threadIdx.x >> 5;
    #pragma unroll
    for (int i = 0; i < 32; i += 8)
        tile[ty + i][tx] = in[(size_t)(r0 + ty + i) * C + c0 + tx];
    __syncthreads();
    #pragma unroll
    for (int i = 0; i < 32; i += 8)
        out[(size_t)(c0 + ty + i) * R + r0 + tx] = f2bf(tile[tx][ty + i]);
}

// ---------------- V transpose: qkv V part -> Vt[b*16+h][64 d][T s] bf16 ----------------
__global__ __launch_bounds__(256) void vtrans_kernel(
    const ushort* __restrict__ qkv, ushort* __restrict__ vt_g, int T)
{
    __shared__ ushort tile[64][72];
    const int sb = blockIdx.x * 64, bh = blockIdx.y;
    const int b = bh >> 4, h = bh & 15;
    const int t = threadIdx.x;
    const int r0 = t >> 3, c0 = (t & 7) * 8;
    const ushort* vsrc = qkv + (size_t)b * T * 3072 + 2048 + h * 64;
    *(s8v*)&tile[r0][c0]      = *(const s8v*)(vsrc + (size_t)(sb + r0) * 3072 + c0);
    *(s8v*)&tile[32 + r0][c0] = *(const s8v*)(vsrc + (size_t)(sb + 32 + r0) * 3072 + c0);
    __syncthreads();
    ushort* vdst = vt_g + (size_t)bh * 64 * T;
    s8v o0, o1;
    #pragma unroll
    for (int j = 0; j < 8; j++) {
        o0[j] = (short)tile[c0 + j][r0];
        o1[j] = (short)tile[c0 + j][32 + r0];
    }
    *(s8v*)(vdst + (size_t)r0 * T + sb + c0)        = o0;
    *(s8v*)(vdst + (size_t)(32 + r0) * T + sb + c0) = o1;
}

// ---------------- bf16 MFMA GEMM (m97 structure): C = A * Bt^T + bias ----------------
// 128x128 tile, BK=64, linear LDS + global_load_lds width-16, 2-barrier loop.
template <bool OUT_BF16>
__global__ __launch_bounds__(256) void gemm_bt_kernel(
    const ushort* __restrict__ A, const ushort* __restrict__ Bt,
    const float* __restrict__ bias, void* __restrict__ Cout,
    int M, int N, int K)
{
    __shared__ ushort As[128][64];   // linear (global_load_lds requires contiguous dest)
    __shared__ ushort Bs[128][64];
    const int t = threadIdx.x;
    const int m0 = blockIdx.y * 128, n0 = blockIdx.x * 128;
    const int wave = t >> 6, lane = t & 63;
    const int lr = lane & 15, lg = lane >> 4;
    const int wm = (wave >> 1) * 64, wn = (wave & 1) * 64;
    const int lrow = lane >> 3;         // 0..7 rows within an 8-row chunk
    const int lcol = (lane & 7) * 8;    // ushort col (16B per lane)

    f4v acc[4][4];
    #pragma unroll
    for (int i = 0; i < 4; i++)
        #pragma unroll
        for (int j = 0; j < 4; j++)
            acc[i][j] = (f4v){0.f, 0.f, 0.f, 0.f};

    for (int k0 = 0; k0 < K; k0 += 64) {
        __syncthreads();
        #pragma unroll
        for (int i = 0; i < 4; i++) {
            int j = wave * 4 + i;       // chunk 0..15, 8 rows each
            int row = j * 8 + lrow;
            gl_lds16(A  + (size_t)(m0 + row) * K + k0 + lcol, &As[j * 8][0]);
            gl_lds16(Bt + (size_t)(n0 + row) * K + k0 + lcol, &Bs[j * 8][0]);
        }
        __syncthreads();                // drains vmcnt before compute
        #pragma unroll
        for (int ks = 0; ks < 64; ks += 32) {
            s8v af[4], bfr[4];
            #pragma unroll
            for (int mb = 0; mb < 4; mb++)
                af[mb] = *reinterpret_cast<const s8v*>(&As[wm + mb * 16 + lr][ks + lg * 8]);
            #pragma unroll
            for (int nb = 0; nb < 4; nb++)
                bfr[nb] = *reinterpret_cast<const s8v*>(&Bs[wn + nb * 16 + lr][ks + lg * 8]);
            #pragma unroll
            for (int mb = 0; mb < 4; mb++)
                #pragma unroll
                for (int nb = 0; nb < 4; nb++)
                    acc[mb][nb] = __builtin_amdgcn_mfma_f32_16x16x32_bf16(af[mb], bfr[nb], acc[mb][nb], 0, 0, 0);
        }
    }

    #pragma unroll
    for (int mb = 0; mb < 4; mb++) {
        #pragma unroll
        for (int nb = 0; nb < 4; nb++) {
            int col = n0 + wn + nb * 16 + lr;
            float bv = bias[col];
            #pragma unroll
            for (int r = 0; r < 4; r++) {
                int row = m0 + wm + mb * 16 + lg * 4 + r;
                float val = acc[mb][nb][r] + bv;
                if (OUT_BF16)
                    reinterpret_cast<ushort*>(Cout)[(size_t)row * N + col] = f2bf(val);
                else
                    reinterpret_cast<float*>(Cout)[(size_t)row * N + col] = val;
            }
        }
    }
}

// ---------------- attention tile compute (one 64-s tile vs one 16-row q slice/wave) ----
__device__ __forceinline__ void attn_tile(
    const s8v qf0, const s8v qf1, int qb, int sb,
    int wave, int lr, int lg,
    const ushort (*Ks)[72], const ushort (*Vs)[72],
    ushort (*pw)[72],                    // p_lds[wave]
    const float* rel_lds,
    float* m_r, float* l_r, f4v* o_acc)
{
    f4v sacc[4];
    #pragma unroll
    for (int cb = 0; cb < 4; cb++) {
        sacc[cb] = (f4v){0.f, 0.f, 0.f, 0.f};
        s8v kf0 = *(const s8v*)&Ks[cb * 16 + lr][lg * 8];
        s8v kf1 = *(const s8v*)&Ks[cb * 16 + lr][32 + lg * 8];
        sacc[cb] = __builtin_amdgcn_mfma_f32_16x16x32_bf16(qf0, kf0, sacc[cb], 0, 0, 0);
        sacc[cb] = __builtin_amdgcn_mfma_f32_16x16x32_bf16(qf1, kf1, sacc[cb], 0, 0, 0);
    }

    if (sb + 192 <= qb) {
        // far tile: all rel distances clip to -128 -> uniform bias, no causal mask
        float c = rel_lds[0];
        #pragma unroll
        for (int cb = 0; cb < 4; cb++)
            #pragma unroll
            for (int r = 0; r < 4; r++)
                sacc[cb][r] = sacc[cb][r] * 0.125f + c;
    } else {
        #pragma unroll
        for (int cb = 0; cb < 4; cb++) {
            int s = sb + cb * 16 + lr;
            #pragma unroll
            for (int r = 0; r < 4; r++) {
                int q = qb + wave * 16 + lg * 4 + r;
                int rel = s - q;
                rel = (rel < -128 ? -128 : (rel > 128 ? 128 : rel)) + 128;
                float val = sacc[cb][r] * 0.125f + rel_lds[rel];
                if (s > q) val = -3.0e38f;
                sacc[cb][r] = val;
            }
        }
    }

    // online softmax per q-row
    #pragma unroll
    for (int r = 0; r < 4; r++) {
        float mx = fmaxf(fmaxf(sacc[0][r], sacc[1][r]), fmaxf(sacc[2][r], sacc[3][r]));
        #pragma unroll
        for (int off = 1; off < 16; off <<= 1)
            mx = fmaxf(mx, __shfl_xor(mx, off, 64));
        float mnew = fmaxf(m_r[r], mx);
        float alpha = exp2f((m_r[r] - mnew) * 1.44269504f);
        m_r[r] = mnew;
        l_r[r] *= alpha;
        #pragma unroll
        for (int d = 0; d < 4; d++) o_acc[d][r] *= alpha;
        float sum = 0.f;
        #pragma unroll
        for (int cb = 0; cb < 4; cb++) {
            float p = exp2f((sacc[cb][r] - mnew) * 1.44269504f);
            sacc[cb][r] = p;
            sum += p;
        }
        #pragma unroll
        for (int off = 1; off < 16; off <<= 1)
            sum += __shfl_xor(sum, off, 64);
        l_r[r] += sum;
    }

    // transpose P through wave-private LDS (acc layout -> A-fragment layout)
    #pragma unroll
    for (int cb = 0; cb < 4; cb++)
        #pragma unroll
        for (int r = 0; r < 4; r++)
            pw[lg * 4 + r][cb * 16 + lr] = f2bf(sacc[cb][r]);

    // O += P V
    #pragma unroll
    for (int ch = 0; ch < 2; ch++) {
        s8v pf = *(const s8v*)&pw[lr][ch * 32 + lg * 8];
        #pragma unroll
        for (int d = 0; d < 4; d++) {
            s8v vf = *(const s8v*)&Vs[d * 16 + lr][ch * 32 + lg * 8];
            o_acc[d] = __builtin_amdgcn_mfma_f32_16x16x32_bf16(pf, vf, o_acc[d], 0, 0, 0);
        }
    }
}

// ---------------- flash attention, paired q-tiles for load balance ----------------
// Grid: (nQ/2, B*16). Block p handles q-tiles lo=p and hi=nQ-1-p (33 tile-iters each).
__global__ __launch_bounds__(256, 2) void attn_kernel(
    const ushort* __restrict__ qkv, const ushort* __restrict__ vt_g,
    const float* __restrict__ rel_emb, ushort* __restrict__ attn_out, int T)
{
    __shared__ ushort Ks[64][72];
    __shared__ ushort Vs[64][72];
    __shared__ ushort p_lds[4][16][72];
    __shared__ float rel_lds[257];

    const int t = threadIdx.x;
    const int nQ = T / 64;
    const int lo = blockIdx.x;          // light q-tile index
    const int hi = nQ - 1 - lo;         // heavy q-tile index
    const int qbL = lo * 64, qbH = hi * 64;
    const int bh = blockIdx.y;
    const int b = bh >> 4, h = bh & 15;
    const size_t rowb = (size_t)b * T;

    for (int i = t; i < 257; i += 256) rel_lds[i] = rel_emb[i * 16 + h];

    const int wave = t >> 6, lane = t & 63;
    const int lr = lane & 15, lg = lane >> 4;
    const int sr = t >> 3, sc = (t & 7) * 8;

    const ushort* kbase = qkv + rowb * 3072 + 1024 + h * 64;
    const ushort* vbase = vt_g + (size_t)bh * 64 * T;

    const ushort* qptrL = qkv + (rowb + qbL + wave * 16 + lr) * 3072 + h * 64;
    s8v qL0 = *(const s8v*)(qptrL + lg * 8);
    s8v qL1 = *(const s8v*)(qptrL + 32 + lg * 8);
    const ushort* qptrH = qkv + (rowb + qbH + wave * 16 + lr) * 3072 + h * 64;
    s8v qH0 = *(const s8v*)(qptrH + lg * 8);
    s8v qH1 = *(const s8v*)(qptrH + 32 + lg * 8);

    float mL[4], lL[4], mH[4], lH[4];
    f4v oL[4], oH[4];
    #pragma unroll
    for (int r = 0; r < 4; r++) { mL[r] = -3.0e38f; lL[r] = 0.f; mH[r] = -3.0e38f; lH[r] = 0.f; }
    #pragma unroll
    for (int d = 0; d < 4; d++) { oL[d] = (f4v){0.f,0.f,0.f,0.f}; oH[d] = (f4v){0.f,0.f,0.f,0.f}; }

    const int nt = hi + 1;

    s8v ka0 = *(const s8v*)(kbase + (size_t)sr * 3072 + sc);
    s8v ka1 = *(const s8v*)(kbase + (size_t)(32 + sr) * 3072 + sc);
    s8v va0 = *(const s8v*)(vbase + (size_t)sr * T + sc);
    s8v va1 = *(const s8v*)(vbase + (size_t)(32 + sr) * T + sc);

    for (int st = 0; st < nt; ++st) {
        const int sb = st * 64;
        __syncthreads();
        *(s8v*)&Ks[sr][sc]      = ka0;
        *(s8v*)&Ks[32 + sr][sc] = ka1;
        *(s8v*)&Vs[sr][sc]      = va0;
        *(s8v*)&Vs[32 + sr][sc] = va1;
        __syncthreads();

        if (st + 1 < nt) {
            const int sn = sb + 64;
            ka0 = *(const s8v*)(kbase + (size_t)(sn + sr) * 3072 + sc);
            ka1 = *(const s8v*)(kbase + (size_t)(sn + 32 + sr) * 3072 + sc);
            va0 = *(const s8v*)(vbase + (size_t)sr * T + sn + sc);
            va1 = *(const s8v*)(vbase + (size_t)(32 + sr) * T + sn + sc);
        }

        attn_tile(qH0, qH1, qbH, sb, wave, lr, lg, Ks, Vs, p_lds[wave], rel_lds, mH, lH, oH);
        if (st <= lo)
            attn_tile(qL0, qL1, qbL, sb, wave, lr, lg, Ks, Vs, p_lds[wave], rel_lds, mL, lL, oL);
    }

    // epilogue: O /= l, store bf16 [B*T][1024]
    #pragma unroll
    for (int r = 0; r < 4; r++) {
        float invH = 1.0f / lH[r];
        float invL = 1.0f / lL[r];
        int rowH = qbH + wave * 16 + lg * 4 + r;
        int rowL = qbL + wave * 16 + lg * 4 + r;
        #pragma unroll
        for (int d = 0; d < 4; d++) {
            attn_out[(rowb + rowH) * 1024 + h * 64 + d * 16 + lr] = f2bf(oH[d][r] * invH);
            attn_out[(rowb + rowL) * 1024 + h * 64 + d * 16 + lr] = f2bf(oL[d][r] * invL);
        }
    }
}

extern "C" void kernel_launch(void* const* d_in, const int* in_sizes, int n_in,
                              void* d_out, int out_size, void* d_ws, size_t ws_size,
                              hipStream_t stream) {
    const float* x       = (const float*)d_in[0];   // [B,T,1024]
    const float* Wqkv    = (const float*)d_in[1];   // [1024,3072]
    const float* bqkv    = (const float*)d_in[2];   // [3072]
    const float* Wout    = (const float*)d_in[3];   // [1024,1024]
    const float* bout    = (const float*)d_in[4];   // [1024]
    const float* rel_emb = (const float*)d_in[5];   // [257,16]
    float* out = (float*)d_out;

    const int M = in_sizes[0] / 1024;   // B*T = 4096
    const int T = 2048;
    const int B = M / T;

    ushort* x_bf = (ushort*)d_ws;                        // M*1024 bf16
    ushort* Wq_t = x_bf + (size_t)M * 1024;              // 3072*1024
    ushort* Wo_t = Wq_t + (size_t)3072 * 1024;           // 1024*1024
    ushort* qkv  = Wo_t + (size_t)1024 * 1024;           // M*3072
    ushort* attn = qkv + (size_t)M * 3072;               // M*1024
    ushort* vt_g = attn + (size_t)M * 1024;              // B*16*64*T = M*1024

    hipLaunchKernelGGL(cast_bf16_kernel, dim3((M * 1024 / 4 + 255) / 256), dim3(256), 0, stream,
                       x, x_bf, M * 1024 / 4);
    hipLaunchKernelGGL(transpose_cast_kernel, dim3(3072 / 32, 1024 / 32), dim3(256), 0, stream,
                       Wqkv, Wq_t, 1024, 3072);
    hipLaunchKernelGGL(transpose_cast_kernel, dim3(1024 / 32, 1024 / 32), dim3(256), 0, stream,
                       Wout, Wo_t, 1024, 1024);
    hipLaunchKernelGGL((gemm_bt_kernel<true>), dim3(3072 / 128, M / 128), dim3(256), 0, stream,
                       x_bf, Wq_t, bqkv, (void*)qkv, M, 3072, 1024);
    hipLaunchKernelGGL(vtrans_kernel, dim3(T / 64, B * 16), dim3(256), 0, stream,
                       qkv, vt_g, T);
    hipLaunchKernelGGL(attn_kernel, dim3((T / 64) / 2, B * 16), dim3(256), 0, stream,
                       qkv, vt_g, rel_emb, attn, T);
    hipLaunchKernelGGL((gemm_bt_kernel<false>), dim3(1024 / 128, M / 128), dim3(256), 0, stream,
                       attn, Wo_t, bout, (void*)out, M, 1024, 1024);
}

// Round 6
// 225.231 us; speedup vs baseline: 1.5771x; 1.1057x over previous
//
#include <hip/hip_runtime.h>
#include <hip/hip_bf16.h>

typedef __attribute__((ext_vector_type(8))) short s8v;   // 8 x bf16 raw (4 VGPRs)
typedef __attribute__((ext_vector_type(4))) float f4v;   // MFMA accumulator

__device__ __forceinline__ ushort f2bf(float f) {
    union { float f; unsigned u; } cv; cv.f = f;
    unsigned u = cv.u;
    unsigned lsb = (u >> 16) & 1u;
    u += 0x7fffu + lsb;          // RNE round to bf16
    return (ushort)(u >> 16);
}

// async global->LDS, 16B per lane; LDS dest is wave-uniform base + lane*16
typedef __attribute__((address_space(1))) void gvoid;
typedef __attribute__((address_space(3))) void lvoid;
__device__ __forceinline__ void gl_lds16(const ushort* g, ushort* l) {
    __builtin_amdgcn_global_load_lds((gvoid*)g, (lvoid*)l, 16, 0, 0);
}

// ---------------- cast fp32 -> bf16 (vectorized) ----------------
__global__ void cast_bf16_kernel(const float* __restrict__ in, ushort* __restrict__ out, int n4) {
    int i = blockIdx.x * blockDim.x + threadIdx.x;
    if (i >= n4) return;
    float4 v = reinterpret_cast<const float4*>(in)[i];
    ushort4 o;
    o.x = f2bf(v.x); o.y = f2bf(v.y); o.z = f2bf(v.z); o.w = f2bf(v.w);
    reinterpret_cast<ushort4*>(out)[i] = o;
}

// ---------------- transpose + cast: in[R][C] fp32 -> out[C][R] bf16 ----------------
__global__ void transpose_cast_kernel(const float* __restrict__ in, ushort* __restrict__ out,
                                      int R, int C) {
    __shared__ float tile[32][33];
    int c0 = blockIdx.x * 32, r0 = blockIdx.y * 32;
    int tx = threadIdx.x & 31, ty = threadIdx.x >> 5;
    #pragma unroll
    for (int i = 0; i < 32; i += 8)
        tile[ty + i][tx] = in[(size_t)(r0 + ty + i) * C + c0 + tx];
    __syncthreads();
    #pragma unroll
    for (int i = 0; i < 32; i += 8)
        out[(size_t)(c0 + ty + i) * R + r0 + tx] = f2bf(tile[tx][ty + i]);
}

// ---------------- V transpose: qkv V part -> Vt[b*16+h][64 d][T s] bf16 ----------------
__global__ __launch_bounds__(256) void vtrans_kernel(
    const ushort* __restrict__ qkv, ushort* __restrict__ vt_g, int T)
{
    __shared__ ushort tile[64][72];
    const int sb = blockIdx.x * 64, bh = blockIdx.y;
    const int b = bh >> 4, h = bh & 15;
    const int t = threadIdx.x;
    const int r0 = t >> 3, c0 = (t & 7) * 8;
    const ushort* vsrc = qkv + (size_t)b * T * 3072 + 2048 + h * 64;
    *(s8v*)&tile[r0][c0]      = *(const s8v*)(vsrc + (size_t)(sb + r0) * 3072 + c0);
    *(s8v*)&tile[32 + r0][c0] = *(const s8v*)(vsrc + (size_t)(sb + 32 + r0) * 3072 + c0);
    __syncthreads();
    ushort* vdst = vt_g + (size_t)bh * 64 * T;
    s8v o0, o1;
    #pragma unroll
    for (int j = 0; j < 8; j++) {
        o0[j] = (short)tile[c0 + j][r0];
        o1[j] = (short)tile[c0 + j][32 + r0];
    }
    *(s8v*)(vdst + (size_t)r0 * T + sb + c0)        = o0;
    *(s8v*)(vdst + (size_t)(32 + r0) * T + sb + c0) = o1;
}

// ---------------- bf16 MFMA GEMM (m97 structure): C = A * Bt^T + bias ----------------
template <bool OUT_BF16>
__global__ __launch_bounds__(256) void gemm_bt_kernel(
    const ushort* __restrict__ A, const ushort* __restrict__ Bt,
    const float* __restrict__ bias, void* __restrict__ Cout,
    int M, int N, int K)
{
    __shared__ ushort As[128][64];   // linear (global_load_lds requires contiguous dest)
    __shared__ ushort Bs[128][64];
    const int t = threadIdx.x;
    const int m0 = blockIdx.y * 128, n0 = blockIdx.x * 128;
    const int wave = t >> 6, lane = t & 63;
    const int lr = lane & 15, lg = lane >> 4;
    const int wm = (wave >> 1) * 64, wn = (wave & 1) * 64;
    const int lrow = lane >> 3;
    const int lcol = (lane & 7) * 8;

    f4v acc[4][4];
    #pragma unroll
    for (int i = 0; i < 4; i++)
        #pragma unroll
        for (int j = 0; j < 4; j++)
            acc[i][j] = (f4v){0.f, 0.f, 0.f, 0.f};

    for (int k0 = 0; k0 < K; k0 += 64) {
        __syncthreads();
        #pragma unroll
        for (int i = 0; i < 4; i++) {
            int j = wave * 4 + i;
            int row = j * 8 + lrow;
            gl_lds16(A  + (size_t)(m0 + row) * K + k0 + lcol, &As[j * 8][0]);
            gl_lds16(Bt + (size_t)(n0 + row) * K + k0 + lcol, &Bs[j * 8][0]);
        }
        __syncthreads();
        #pragma unroll
        for (int ks = 0; ks < 64; ks += 32) {
            s8v af[4], bfr[4];
            #pragma unroll
            for (int mb = 0; mb < 4; mb++)
                af[mb] = *reinterpret_cast<const s8v*>(&As[wm + mb * 16 + lr][ks + lg * 8]);
            #pragma unroll
            for (int nb = 0; nb < 4; nb++)
                bfr[nb] = *reinterpret_cast<const s8v*>(&Bs[wn + nb * 16 + lr][ks + lg * 8]);
            #pragma unroll
            for (int mb = 0; mb < 4; mb++)
                #pragma unroll
                for (int nb = 0; nb < 4; nb++)
                    acc[mb][nb] = __builtin_amdgcn_mfma_f32_16x16x32_bf16(af[mb], bfr[nb], acc[mb][nb], 0, 0, 0);
        }
    }

    #pragma unroll
    for (int mb = 0; mb < 4; mb++) {
        #pragma unroll
        for (int nb = 0; nb < 4; nb++) {
            int col = n0 + wn + nb * 16 + lr;
            float bv = bias[col];
            #pragma unroll
            for (int r = 0; r < 4; r++) {
                int row = m0 + wm + mb * 16 + lg * 4 + r;
                float val = acc[mb][nb][r] + bv;
                if (OUT_BF16)
                    reinterpret_cast<ushort*>(Cout)[(size_t)row * N + col] = f2bf(val);
                else
                    reinterpret_cast<float*>(Cout)[(size_t)row * N + col] = val;
            }
        }
    }
}

// ---------------- swapped-operand attention tile ----------------
// S^T = K·Q^T via mfma(K,Q): lane owns q = qb+wave*16+lr, s = sb+cb*16+lg*4+r.
// Softmax fully per-lane (15 fmax in-lane + 2 shfl). O^T accumulated via mfma(V^T, P^T).
__device__ __forceinline__ void attn_tile_sw(
    const s8v qf0, const s8v qf1, int q_abs, int qb, int sb,
    int lr, int lg,
    const ushort (*Ks)[72], const ushort (*Vs)[72],
    ushort (*pT)[72],                    // per-wave [16 q][72] scratch
    const float* rel_lds,                // rel_emb * log2e
    float& m, float& l, f4v* oT)
{
    const float SC = 0.125f * 1.44269504f;   // qk-scale * log2e
    f4v sacc[4];
    __builtin_amdgcn_s_setprio(1);
    #pragma unroll
    for (int cb = 0; cb < 4; cb++) {
        sacc[cb] = (f4v){0.f, 0.f, 0.f, 0.f};
        s8v kf0 = *(const s8v*)&Ks[cb * 16 + lr][lg * 8];
        s8v kf1 = *(const s8v*)&Ks[cb * 16 + lr][32 + lg * 8];
        sacc[cb] = __builtin_amdgcn_mfma_f32_16x16x32_bf16(kf0, qf0, sacc[cb], 0, 0, 0);
        sacc[cb] = __builtin_amdgcn_mfma_f32_16x16x32_bf16(kf1, qf1, sacc[cb], 0, 0, 0);
    }
    __builtin_amdgcn_s_setprio(0);

    if (sb + 192 <= qb) {
        // far tile: all rel distances clip to -128 -> uniform bias, no causal mask
        float c = rel_lds[0];
        #pragma unroll
        for (int cb = 0; cb < 4; cb++)
            #pragma unroll
            for (int r = 0; r < 4; r++)
                sacc[cb][r] = sacc[cb][r] * SC + c;
    } else {
        #pragma unroll
        for (int cb = 0; cb < 4; cb++) {
            #pragma unroll
            for (int r = 0; r < 4; r++) {
                int s = sb + cb * 16 + lg * 4 + r;
                int rel = s - q_abs;
                rel = (rel < -128 ? -128 : (rel > 128 ? 128 : rel)) + 128;
                float val = sacc[cb][r] * SC + rel_lds[rel];
                if (s > q_abs) val = -3.0e38f;
                sacc[cb][r] = val;
            }
        }
    }

    // row max: in-lane tree over 16 + 2 shfl across the 4 lg-lanes
    float pm0 = fmaxf(fmaxf(sacc[0][0], sacc[0][1]), fmaxf(sacc[0][2], sacc[0][3]));
    float pm1 = fmaxf(fmaxf(sacc[1][0], sacc[1][1]), fmaxf(sacc[1][2], sacc[1][3]));
    float pm2 = fmaxf(fmaxf(sacc[2][0], sacc[2][1]), fmaxf(sacc[2][2], sacc[2][3]));
    float pm3 = fmaxf(fmaxf(sacc[3][0], sacc[3][1]), fmaxf(sacc[3][2], sacc[3][3]));
    float pm = fmaxf(fmaxf(pm0, pm1), fmaxf(pm2, pm3));
    pm = fmaxf(pm, __shfl_xor(pm, 16, 64));
    pm = fmaxf(pm, __shfl_xor(pm, 32, 64));

    // defer-max (T13): only rescale when the running max grew by > 8 (log2 units)
    if (__any(pm > m + 8.0f)) {
        float mnew = fmaxf(m, pm);
        float alpha = exp2f(m - mnew);
        l *= alpha;
        #pragma unroll
        for (int d = 0; d < 4; d++)
            #pragma unroll
            for (int r = 0; r < 4; r++)
                oT[d][r] *= alpha;
        m = mnew;
    }

    // p = exp2(s - m); in-lane sum + 2 shfl
    float sum = 0.f;
    #pragma unroll
    for (int cb = 0; cb < 4; cb++) {
        #pragma unroll
        for (int r = 0; r < 4; r++) {
            float p = exp2f(sacc[cb][r] - m);
            sacc[cb][r] = p;
            sum += p;
        }
    }
    sum += __shfl_xor(sum, 16, 64);
    sum += __shfl_xor(sum, 32, 64);
    l += sum;

    // pack P^T -> per-wave LDS: pT[q=lr][s], 4 x ds_write_b64
    #pragma unroll
    for (int cb = 0; cb < 4; cb++) {
        unsigned lo = (unsigned)f2bf(sacc[cb][0]) | ((unsigned)f2bf(sacc[cb][1]) << 16);
        unsigned hi = (unsigned)f2bf(sacc[cb][2]) | ((unsigned)f2bf(sacc[cb][3]) << 16);
        *(unsigned long long*)&pT[lr][cb * 16 + lg * 4] =
            (unsigned long long)lo | ((unsigned long long)hi << 32);
    }

    // O^T += V^T · P^T  (A = V^T frag row=d, B = P^T frag col=q)
    __builtin_amdgcn_s_setprio(1);
    #pragma unroll
    for (int ch = 0; ch < 2; ch++) {
        s8v pf = *(const s8v*)&pT[lr][ch * 32 + lg * 8];
        #pragma unroll
        for (int d = 0; d < 4; d++) {
            s8v vf = *(const s8v*)&Vs[d * 16 + lr][ch * 32 + lg * 8];
            oT[d] = __builtin_amdgcn_mfma_f32_16x16x32_bf16(vf, pf, oT[d], 0, 0, 0);
        }
    }
    __builtin_amdgcn_s_setprio(0);
}

// normalize O^T, transpose through per-wave LDS, coalesced store
__device__ __forceinline__ void store_O(
    f4v* oT, float l, int lr, int lg, int lane, int wave,
    ushort (*pT)[72], int qb, size_t rowb, int h, ushort* __restrict__ attn_out)
{
    float inv = 1.0f / l;
    #pragma unroll
    for (int d = 0; d < 4; d++) {
        unsigned lo = (unsigned)f2bf(oT[d][0] * inv) | ((unsigned)f2bf(oT[d][1] * inv) << 16);
        unsigned hi = (unsigned)f2bf(oT[d][2] * inv) | ((unsigned)f2bf(oT[d][3] * inv) << 16);
        *(unsigned long long*)&pT[lr][d * 16 + lg * 4] =
            (unsigned long long)lo | ((unsigned long long)hi << 32);
    }
    int q_r = lane >> 2, part = lane & 3;
    s8v a = *(const s8v*)&pT[q_r][part * 16];
    s8v b = *(const s8v*)&pT[q_r][part * 16 + 8];
    ushort* dst = attn_out + (rowb + qb + wave * 16 + q_r) * 1024 + h * 64 + part * 16;
    *(s8v*)dst = a;
    *(s8v*)(dst + 8) = b;
}

// ---------------- flash attention, paired q-tiles, swapped softmax ----------------
__global__ __launch_bounds__(256, 2) void attn_kernel(
    const ushort* __restrict__ qkv, const ushort* __restrict__ vt_g,
    const float* __restrict__ rel_emb, ushort* __restrict__ attn_out, int T)
{
    __shared__ ushort Ks[64][72];
    __shared__ ushort Vs[64][72];
    __shared__ ushort p_lds[4][16][72];
    __shared__ float rel_lds[257];

    const int t = threadIdx.x;
    const int nQ = T / 64;
    const int lo = blockIdx.x;
    const int hi = nQ - 1 - lo;
    const int qbL = lo * 64, qbH = hi * 64;
    const int bh = blockIdx.y;
    const int b = bh >> 4, h = bh & 15;
    const size_t rowb = (size_t)b * T;

    for (int i = t; i < 257; i += 256) rel_lds[i] = rel_emb[i * 16 + h] * 1.44269504f;

    const int wave = t >> 6, lane = t & 63;
    const int lr = lane & 15, lg = lane >> 4;
    const int sr = t >> 3, sc = (t & 7) * 8;

    const ushort* kbase = qkv + rowb * 3072 + 1024 + h * 64;
    const ushort* vbase = vt_g + (size_t)bh * 64 * T;

    const int qaL = qbL + wave * 16 + lr;
    const int qaH = qbH + wave * 16 + lr;
    const ushort* qptrL = qkv + (rowb + qaL) * 3072 + h * 64;
    s8v qL0 = *(const s8v*)(qptrL + lg * 8);
    s8v qL1 = *(const s8v*)(qptrL + 32 + lg * 8);
    const ushort* qptrH = qkv + (rowb + qaH) * 3072 + h * 64;
    s8v qH0 = *(const s8v*)(qptrH + lg * 8);
    s8v qH1 = *(const s8v*)(qptrH + 32 + lg * 8);

    float mL = -3.0e38f, lL = 0.f, mH = -3.0e38f, lH = 0.f;
    f4v oL[4], oH[4];
    #pragma unroll
    for (int d = 0; d < 4; d++) { oL[d] = (f4v){0.f,0.f,0.f,0.f}; oH[d] = (f4v){0.f,0.f,0.f,0.f}; }

    const int nt = hi + 1;

    s8v ka0 = *(const s8v*)(kbase + (size_t)sr * 3072 + sc);
    s8v ka1 = *(const s8v*)(kbase + (size_t)(32 + sr) * 3072 + sc);
    s8v va0 = *(const s8v*)(vbase + (size_t)sr * T + sc);
    s8v va1 = *(const s8v*)(vbase + (size_t)(32 + sr) * T + sc);

    for (int st = 0; st < nt; ++st) {
        const int sb = st * 64;
        __syncthreads();
        *(s8v*)&Ks[sr][sc]      = ka0;
        *(s8v*)&Ks[32 + sr][sc] = ka1;
        *(s8v*)&Vs[sr][sc]      = va0;
        *(s8v*)&Vs[32 + sr][sc] = va1;
        __syncthreads();

        if (st + 1 < nt) {
            const int sn = sb + 64;
            ka0 = *(const s8v*)(kbase + (size_t)(sn + sr) * 3072 + sc);
            ka1 = *(const s8v*)(kbase + (size_t)(sn + 32 + sr) * 3072 + sc);
            va0 = *(const s8v*)(vbase + (size_t)sr * T + sn + sc);
            va1 = *(const s8v*)(vbase + (size_t)(32 + sr) * T + sn + sc);
        }

        attn_tile_sw(qH0, qH1, qaH, qbH, sb, lr, lg, Ks, Vs, p_lds[wave], rel_lds, mH, lH, oH);
        if (st <= lo)
            attn_tile_sw(qL0, qL1, qaL, qbL, sb, lr, lg, Ks, Vs, p_lds[wave], rel_lds, mL, lL, oL);
    }

    store_O(oH, lH, lr, lg, lane, wave, p_lds[wave], qbH, rowb, h, attn_out);
    store_O(oL, lL, lr, lg, lane, wave, p_lds[wave], qbL, rowb, h, attn_out);
}

extern "C" void kernel_launch(void* const* d_in, const int* in_sizes, int n_in,
                              void* d_out, int out_size, void* d_ws, size_t ws_size,
                              hipStream_t stream) {
    const float* x       = (const float*)d_in[0];   // [B,T,1024]
    const float* Wqkv    = (const float*)d_in[1];   // [1024,3072]
    const float* bqkv    = (const float*)d_in[2];   // [3072]
    const float* Wout    = (const float*)d_in[3];   // [1024,1024]
    const float* bout    = (const float*)d_in[4];   // [1024]
    const float* rel_emb = (const float*)d_in[5];   // [257,16]
    float* out = (float*)d_out;

    const int M = in_sizes[0] / 1024;   // B*T = 4096
    const int T = 2048;
    const int B = M / T;

    ushort* x_bf = (ushort*)d_ws;                        // M*1024 bf16
    ushort* Wq_t = x_bf + (size_t)M * 1024;              // 3072*1024
    ushort* Wo_t = Wq_t + (size_t)3072 * 1024;           // 1024*1024
    ushort* qkv  = Wo_t + (size_t)1024 * 1024;           // M*3072
    ushort* attn = qkv + (size_t)M * 3072;               // M*1024
    ushort* vt_g = attn + (size_t)M * 1024;              // B*16*64*T = M*1024

    hipLaunchKernelGGL(cast_bf16_kernel, dim3((M * 1024 / 4 + 255) / 256), dim3(256), 0, stream,
                       x, x_bf, M * 1024 / 4);
    hipLaunchKernelGGL(transpose_cast_kernel, dim3(3072 / 32, 1024 / 32), dim3(256), 0, stream,
                       Wqkv, Wq_t, 1024, 3072);
    hipLaunchKernelGGL(transpose_cast_kernel, dim3(1024 / 32, 1024 / 32), dim3(256), 0, stream,
                       Wout, Wo_t, 1024, 1024);
    hipLaunchKernelGGL((gemm_bt_kernel<true>), dim3(3072 / 128, M / 128), dim3(256), 0, stream,
                       x_bf, Wq_t, bqkv, (void*)qkv, M, 3072, 1024);
    hipLaunchKernelGGL(vtrans_kernel, dim3(T / 64, B * 16), dim3(256), 0, stream,
                       qkv, vt_g, T);
    hipLaunchKernelGGL(attn_kernel, dim3((T / 64) / 2, B * 16), dim3(256), 0, stream,
                       qkv, vt_g, rel_emb, attn, T);
    hipLaunchKernelGGL((gemm_bt_kernel<false>), dim3(1024 / 128, M / 128), dim3(256), 0, stream,
                       attn, Wo_t, bout, (void*)out, M, 1024, 1024);
}